// Round 2
// baseline (128.458 us; speedup 1.0000x reference)
//
#include <hip/hip_runtime.h>
#include <math.h>

#define WCELLS 10          // raster window cells per dim
#define WAVES_PER_BLOCK 4
#define BLOCK 256

typedef float f32x4 __attribute__((ext_vector_type(4)));

__global__ __launch_bounds__(BLOCK) void raster_kernel(
    const float* __restrict__ sigma,    // [N,3]
    const float* __restrict__ time_,    // [N]
    const float* __restrict__ charge,   // [N]
    const float* __restrict__ tail,     // [N,3]
    const float* __restrict__ gsp,      // [3]
    float* __restrict__ out_r,          // [N,10,10,10]
    float* __restrict__ out_off,        // [N,3] written as float values
    int n, int niter)
{
    // per-wave scratch
    __shared__ float s_w01[WAVES_PER_BLOCK][2][12];   // w0, w1 (padded)
    __shared__ float s_w2 [WAVES_PER_BLOCK][12];      // w2
    __shared__ float s_qw01[WAVES_PER_BLOCK][100];    // charge * w0[i0] * w1[i1]

    const int wave = threadIdx.x >> 6;
    const int lane = threadIdx.x & 63;
    const int nwaves = gridDim.x * WAVES_PER_BLOCK;
    int d = blockIdx.x * WAVES_PER_BLOCK + wave;

    const float g0 = gsp[0], g1 = gsp[1], g2 = gsp[2];

    for (int it = 0; it < niter; ++it, d += nwaves) {
        const bool active = (d < n);

        // ---- phase A: 33 edge CDFs, shuffle-diff to weights ----
        const int dim = lane / 11;          // 0..2 for lane<33
        const int k   = lane - dim * 11;    // 0..10
        float cdf = 0.0f, iminf = 0.0f;
        if (active && lane < 33) {
            float pt = (dim == 0) ? tail[(size_t)d*3 + 1]
                     : (dim == 1) ? tail[(size_t)d*3 + 2]
                     : time_[d];
            float sg = sigma[(size_t)d*3 + dim];
            float g  = (dim == 0) ? g0 : (dim == 1) ? g1 : g2;
            iminf = floorf((pt - 3.0f * sg) / g);
            float edge = (iminf + (float)k) * g;
            float z = (edge - pt) / (sg * 1.4142135623730951f);
            cdf = 0.5f * (1.0f + erff(z));
        }
        float cdf1 = __shfl_down(cdf, 1);   // cdf of edge k+1 (same dim for k<10)
        if (active && lane < 33) {
            if (k < 10) {
                float wv = cdf1 - cdf;
                if (dim < 2) s_w01[wave][dim][k] = wv;
                else         s_w2 [wave][k]      = wv;
            }
            if (k == 0) {
                out_off[(size_t)d*3 + dim] = iminf;   // integer value, f32 encoding
            }
        }
        __syncthreads();

        // ---- phase A2: fold charge into 100-entry qw01 table ----
        if (active) {
            float q = charge[d];
            int i = lane;                       // 0..63 < 100
            s_qw01[wave][i] = q * s_w01[wave][0][i/10] * s_w01[wave][1][i%10];
            int i2 = lane + 64;
            if (i2 < 100)
                s_qw01[wave][i2] = q * s_w01[wave][0][i2/10] * s_w01[wave][1][i2%10];
        }
        __syncthreads();

        // ---- phase B: stream 1000 floats as 250 float4 nontemporal stores ----
        if (active) {
            float* base = out_r + (size_t)d * 1000;
            const float* qw = s_qw01[wave];
            const float* w2 = s_w2[wave];
            #pragma unroll
            for (int cc = 0; cc < 4; ++cc) {
                int c = lane + cc * 64;
                if (c < 250) {
                    int f = 4 * c;
                    f32x4 v;
                    v.x = qw[(f    ) / 10] * w2[(f    ) % 10];
                    v.y = qw[(f + 1) / 10] * w2[(f + 1) % 10];
                    v.z = qw[(f + 2) / 10] * w2[(f + 2) % 10];
                    v.w = qw[(f + 3) / 10] * w2[(f + 3) % 10];
                    __builtin_nontemporal_store(v, reinterpret_cast<f32x4*>(base + f));
                }
            }
        }
        __syncthreads();
    }
}

extern "C" void kernel_launch(void* const* d_in, const int* in_sizes, int n_in,
                              void* d_out, int out_size, void* d_ws, size_t ws_size,
                              hipStream_t stream) {
    const float* sigma  = (const float*)d_in[0];
    const float* time_  = (const float*)d_in[1];
    const float* charge = (const float*)d_in[2];
    const float* tail   = (const float*)d_in[3];
    const float* gsp    = (const float*)d_in[4];

    const int n = in_sizes[1];          // N depos (time is [N])
    float* out_r   = (float*)d_out;
    float* out_off = out_r + (size_t)n * (WCELLS * WCELLS * WCELLS);

    const int blocks = 4096;            // 16384 waves -> 8 depos/wave at N=131072
    const int nwaves = blocks * WAVES_PER_BLOCK;
    const int niter  = (n + nwaves - 1) / nwaves;

    raster_kernel<<<blocks, BLOCK, 0, stream>>>(sigma, time_, charge, tail, gsp,
                                                out_r, out_off, n, niter);
}

// Round 3
// 110.199 us; speedup vs baseline: 1.1657x; 1.1657x over previous
//
#include <hip/hip_runtime.h>
#include <math.h>

#define WCELLS 10          // raster window cells per dim
#define WAVES_PER_BLOCK 4
#define BLOCK 256

typedef float f32x4 __attribute__((ext_vector_type(4)));

__global__ __launch_bounds__(BLOCK) void raster_kernel(
    const float* __restrict__ sigma,    // [N,3]
    const float* __restrict__ time_,    // [N]
    const float* __restrict__ charge,   // [N]
    const float* __restrict__ tail,     // [N,3]
    const float* __restrict__ gsp,      // [3]
    float* __restrict__ out_r,          // [N,10,10,10]
    float* __restrict__ out_off,        // [N,3] written as float values
    int n, int niter)
{
    // per-wave scratch
    __shared__ float s_w01[WAVES_PER_BLOCK][2][12];   // w0, w1 (padded)
    __shared__ float s_w2 [WAVES_PER_BLOCK][12];      // w2
    __shared__ float s_qw01[WAVES_PER_BLOCK][100];    // charge * w0[i0] * w1[i1]

    const int wave = threadIdx.x >> 6;
    const int lane = threadIdx.x & 63;
    const int nwaves = gridDim.x * WAVES_PER_BLOCK;
    int d = blockIdx.x * WAVES_PER_BLOCK + wave;

    const float g0 = gsp[0], g1 = gsp[1], g2 = gsp[2];

    for (int it = 0; it < niter; ++it, d += nwaves) {
        const bool active = (d < n);

        // ---- phase A: 33 edge CDFs, shuffle-diff to weights ----
        const int dim = lane / 11;          // 0..2 for lane<33
        const int k   = lane - dim * 11;    // 0..10
        float cdf = 0.0f, iminf = 0.0f;
        if (active && lane < 33) {
            float pt = (dim == 0) ? tail[(size_t)d*3 + 1]
                     : (dim == 1) ? tail[(size_t)d*3 + 2]
                     : time_[d];
            float sg = sigma[(size_t)d*3 + dim];
            float g  = (dim == 0) ? g0 : (dim == 1) ? g1 : g2;
            iminf = floorf((pt - 3.0f * sg) / g);
            float edge = (iminf + (float)k) * g;
            float z = (edge - pt) / (sg * 1.4142135623730951f);
            cdf = 0.5f * (1.0f + erff(z));
        }
        float cdf1 = __shfl_down(cdf, 1);   // cdf of edge k+1 (same dim for k<10)
        if (active && lane < 33) {
            if (k < 10) {
                float wv = cdf1 - cdf;
                if (dim < 2) s_w01[wave][dim][k] = wv;
                else         s_w2 [wave][k]      = wv;
            }
            if (k == 0) {
                out_off[(size_t)d*3 + dim] = iminf;   // integer value, f32 encoding
            }
        }
        __syncthreads();

        // ---- phase A2: fold charge into 100-entry qw01 table ----
        if (active) {
            float q = charge[d];
            int i = lane;                       // 0..63 < 100
            s_qw01[wave][i] = q * s_w01[wave][0][i/10] * s_w01[wave][1][i%10];
            int i2 = lane + 64;
            if (i2 < 100)
                s_qw01[wave][i2] = q * s_w01[wave][0][i2/10] * s_w01[wave][1][i2%10];
        }
        __syncthreads();

        // ---- phase B: stream 1000 floats as 250 float4 plain stores ----
        if (active) {
            float* base = out_r + (size_t)d * 1000;
            const float* qw = s_qw01[wave];
            const float* w2 = s_w2[wave];
            #pragma unroll
            for (int cc = 0; cc < 4; ++cc) {
                int c = lane + cc * 64;
                if (c < 250) {
                    int f = 4 * c;
                    f32x4 v;
                    v.x = qw[(f    ) / 10] * w2[(f    ) % 10];
                    v.y = qw[(f + 1) / 10] * w2[(f + 1) % 10];
                    v.z = qw[(f + 2) / 10] * w2[(f + 2) % 10];
                    v.w = qw[(f + 3) / 10] * w2[(f + 3) % 10];
                    *reinterpret_cast<f32x4*>(base + f) = v;
                }
            }
        }
        __syncthreads();
    }
}

extern "C" void kernel_launch(void* const* d_in, const int* in_sizes, int n_in,
                              void* d_out, int out_size, void* d_ws, size_t ws_size,
                              hipStream_t stream) {
    const float* sigma  = (const float*)d_in[0];
    const float* time_  = (const float*)d_in[1];
    const float* charge = (const float*)d_in[2];
    const float* tail   = (const float*)d_in[3];
    const float* gsp    = (const float*)d_in[4];

    const int n = in_sizes[1];          // N depos (time is [N])
    float* out_r   = (float*)d_out;
    float* out_off = out_r + (size_t)n * (WCELLS * WCELLS * WCELLS);

    const int blocks = 4096;            // 16384 waves -> 8 depos/wave at N=131072
    const int nwaves = blocks * WAVES_PER_BLOCK;
    const int niter  = (n + nwaves - 1) / nwaves;

    raster_kernel<<<blocks, BLOCK, 0, stream>>>(sigma, time_, charge, tail, gsp,
                                                out_r, out_off, n, niter);
}